// Round 11
// baseline (230.135 us; speedup 1.0000x reference)
//
#include <hip/hip_runtime.h>
#include <hip/hip_bf16.h>

#define KNBR 20

typedef unsigned short u16;
typedef __attribute__((ext_vector_type(8))) short bf16x8;   // 8 bf16 = 4 VGPR
typedef __attribute__((ext_vector_type(4))) float f32x4;    // MFMA C/D frag

// ---- runtime index-width detection (proven in round 5) ----
__device__ __forceinline__ bool idx_is64(const unsigned int* w) {
    return (w[1] | w[3] | w[5] | w[7] | w[9] | w[11] | w[13] | w[15]) == 0u;
}
__device__ __forceinline__ int idx_at(const int* p, bool is64, long long i) {
    return is64 ? p[2 * i] : p[i];
}

__device__ __forceinline__ u16 f2bf(float x) {
    union { __hip_bfloat16 b; u16 u; } cv;
    cv.b = __float2bfloat16(x);
    return cv.u;
}
__device__ __forceinline__ float blo2f(unsigned int w) {      // low bf16 -> f32
    union { float f; unsigned int i; } c; c.i = w << 16; return c.f;
}
__device__ __forceinline__ float bhi2f(unsigned int w) {      // high bf16 -> f32
    union { float f; unsigned int i; } c; c.i = w & 0xffff0000u; return c.f;
}

// ---------------- K0a: cast weights fp32 -> bf16 (tiny) ----------------
__global__ void __launch_bounds__(256) k_cast_w(
    const float* __restrict__ Wn, const float* __restrict__ Wf,
    u16* __restrict__ Wnb, u16* __restrict__ Wfb)
{
    int i = blockIdx.x * 256 + threadIdx.x;      // 196608 total
    if (i < 65536)       Wnb[i] = f2bf(Wn[i]);
    else if (i < 196608) Wfb[i - 65536] = f2bf(Wf[i - 65536]);
}

// ---------------- K0b: cast X fp32 -> bf16 (float4 -> ushort4 per thread) ----
__global__ void __launch_bounds__(256) k_cast_x(
    const float* __restrict__ X, u16* __restrict__ Xb, int n4)
{
    int i = blockIdx.x * 256 + threadIdx.x;
    if (i < n4) {
        float4 v = ((const float4*)X)[i];
        ushort4 o;
        o.x = f2bf(v.x); o.y = f2bf(v.y); o.z = f2bf(v.z); o.w = f2bf(v.w);
        ((ushort4*)Xb)[i] = o;
    }
}

// ---------------- K1: gather-mean over bf16 X -> bf16 mean ----------------
// 2 rows per wave: half-wave (32 lanes) x 16B = one 512B bf16 row per gather.
__global__ void __launch_bounds__(256) k_gather_mean(
    const u16* __restrict__ Xb, const int* __restrict__ sub_nodes,
    const int* __restrict__ nbr, const int* __restrict__ g2s,
    u16* __restrict__ mean_b, int M)
{
    const bool is64 = idx_is64((const unsigned int*)nbr);
    const int lane = threadIdx.x & 63;
    const int wid  = threadIdx.x >> 6;       // wave in block: 0..3
    const int half = lane >> 5;              // 0/1: which row of the pair
    const int l31  = lane & 31;
    const int row  = blockIdx.x * 8 + wid * 2 + half;
    const int rowc = (row < M) ? row : (M - 1);

    const int g = idx_at(sub_nodes, is64, rowc);
    int s_my = rowc;
    if (l31 < KNBR) {
        int nid = idx_at(nbr, is64, (long long)g * KNBR + l31);
        int s   = idx_at(g2s, is64, nid);
        s_my = (s < 0) ? rowc : s;
    }

    float acc[8] = {0.f, 0.f, 0.f, 0.f, 0.f, 0.f, 0.f, 0.f};
    const int sbase = half << 5;             // shfl source base for this half
    #pragma unroll
    for (int k = 0; k < KNBR; ++k) {
        const int sk = __shfl(s_my, sbase + k, 64);
        const uint4 v = ((const uint4*)(Xb + (size_t)sk * 256))[l31];
        acc[0] += blo2f(v.x); acc[1] += bhi2f(v.x);
        acc[2] += blo2f(v.y); acc[3] += bhi2f(v.y);
        acc[4] += blo2f(v.z); acc[5] += bhi2f(v.z);
        acc[6] += blo2f(v.w); acc[7] += bhi2f(v.w);
    }
    if (row < M) {
        const float inv = 1.0f / (float)KNBR;
        uint4 o;
        o.x = (unsigned)f2bf(acc[0] * inv) | ((unsigned)f2bf(acc[1] * inv) << 16);
        o.y = (unsigned)f2bf(acc[2] * inv) | ((unsigned)f2bf(acc[3] * inv) << 16);
        o.z = (unsigned)f2bf(acc[4] * inv) | ((unsigned)f2bf(acc[5] * inv) << 16);
        o.w = (unsigned)f2bf(acc[6] * inv) | ((unsigned)f2bf(acc[7] * inv) << 16);
        ((uint4*)(mean_b + (size_t)row * 256))[l31] = o;
    }
}

// ---------------- K2/K3: MFMA GEMM  C = relu(A @ W^T + bias) ----------------
// BM=64 (was 128): grid 782 blocks -> 6.1 waves/SIMD available (was 3.05).
// Round-10 counters showed the GEMM latency-bound at OccupancyPercent 17.6
// (grid-limited TLP), MfmaUtil 5.5, VALUBusy 7 -- all pipes idle.
// Block: 512 thr = 8 waves (2M x 4N), wave = 32x64 out, BN=256 (full row).
// MODE 0: relu -> bf16 Hb.   MODE 1: relu -> row-L2-normalize -> fp32 Out.
template<int KTOT, int MODE>
__global__ void __launch_bounds__(512) k_gemm(
    const u16* __restrict__ A0, const u16* __restrict__ A1,
    const u16* __restrict__ B, const float* __restrict__ bias,
    u16* __restrict__ Hb, float* __restrict__ Out, int M)
{
    const int t    = threadIdx.x;
    const int lane = t & 63;
    const int w    = t >> 6;        // 0..7
    const int wm   = w >> 2;        // 0..1  (M dir, 32 rows each)
    const int wn   = w & 3;         // 0..3  (N dir, 64 cols each)
    const int l15  = lane & 15;
    const int lk8  = (lane >> 4) << 3;   // k sub-offset: 0,8,16,24
    const int rsub = (lane >> 4) << 2;   // C row sub-offset: 0,4,8,12
    const int m0   = blockIdx.x * 64;

    int ra[2];                           // clamped A rows per m-fragment
    #pragma unroll
    for (int fm = 0; fm < 2; ++fm) {
        int r = m0 + wm * 32 + fm * 16 + l15;
        ra[fm] = (r < M) ? r : (M - 1);
    }

    f32x4 acc[2][4];
    #pragma unroll
    for (int i = 0; i < 2; ++i)
        #pragma unroll
        for (int j = 0; j < 4; ++j)
            acc[i][j] = (f32x4)(0.f);

    // B fragment rows: W[wn*64 + fn*16 + l15][k], 16B contiguous per lane
    const u16* bbase = B + (size_t)(wn * 64 + l15) * KTOT + lk8;

    // ---- K loop, first 256 cols from A0 ----
    #pragma unroll
    for (int k0 = 0; k0 < 256; k0 += 32) {
        bf16x8 af[2], bfr[4];
        #pragma unroll
        for (int fm = 0; fm < 2; ++fm)
            af[fm] = *(const bf16x8*)(A0 + (size_t)ra[fm] * 256 + k0 + lk8);
        #pragma unroll
        for (int fn = 0; fn < 4; ++fn)
            bfr[fn] = *(const bf16x8*)(bbase + (size_t)fn * 16 * KTOT + k0);
        #pragma unroll
        for (int fm = 0; fm < 2; ++fm)
            #pragma unroll
            for (int fn = 0; fn < 4; ++fn)
                acc[fm][fn] = __builtin_amdgcn_mfma_f32_16x16x32_bf16(
                    af[fm], bfr[fn], acc[fm][fn], 0, 0, 0);
    }
    // ---- second 256 cols from A1 (KTOT==512 only) ----
    if (KTOT == 512) {
        #pragma unroll
        for (int k0 = 0; k0 < 256; k0 += 32) {
            bf16x8 af[2], bfr[4];
            #pragma unroll
            for (int fm = 0; fm < 2; ++fm)
                af[fm] = *(const bf16x8*)(A1 + (size_t)ra[fm] * 256 + k0 + lk8);
            #pragma unroll
            for (int fn = 0; fn < 4; ++fn)
                bfr[fn] = *(const bf16x8*)(bbase + (size_t)fn * 16 * KTOT + 256 + k0);
            #pragma unroll
            for (int fm = 0; fm < 2; ++fm)
                #pragma unroll
                for (int fn = 0; fn < 4; ++fn)
                    acc[fm][fn] = __builtin_amdgcn_mfma_f32_16x16x32_bf16(
                        af[fm], bfr[fn], acc[fm][fn], 0, 0, 0);
        }
    }

    if (MODE == 0) {
        // relu -> bf16 h
        #pragma unroll
        for (int fn = 0; fn < 4; ++fn) {
            const int col = wn * 64 + fn * 16 + l15;
            const float bv = bias[col];
            #pragma unroll
            for (int fm = 0; fm < 2; ++fm) {
                const int rb = m0 + wm * 32 + fm * 16 + rsub;
                #pragma unroll
                for (int r = 0; r < 4; ++r) {
                    const int row = rb + r;
                    if (row < M) {
                        float v = fmaxf(acc[fm][fn][r] + bv, 0.f);
                        Hb[(size_t)row * 256 + col] = f2bf(v);
                    }
                }
            }
        }
    } else {
        // relu -> row L2-normalize -> fp32 out (BN==256 covers full row)
        __shared__ __align__(16) float sums[64][4];
        float part[2][4];
        #pragma unroll
        for (int fm = 0; fm < 2; ++fm)
            #pragma unroll
            for (int r = 0; r < 4; ++r)
                part[fm][r] = 0.f;

        #pragma unroll
        for (int fn = 0; fn < 4; ++fn) {
            const float bv = bias[wn * 64 + fn * 16 + l15];
            #pragma unroll
            for (int fm = 0; fm < 2; ++fm)
                #pragma unroll
                for (int r = 0; r < 4; ++r) {
                    float v = fmaxf(acc[fm][fn][r] + bv, 0.f);
                    acc[fm][fn][r] = v;
                    part[fm][r] += v * v;
                }
        }
        // sum over the wave's 64 cols (16 col-lanes x 4 fn already in-reg)
        #pragma unroll
        for (int fm = 0; fm < 2; ++fm)
            #pragma unroll
            for (int r = 0; r < 4; ++r) {
                float s = part[fm][r];
                s += __shfl_xor(s, 1, 64);
                s += __shfl_xor(s, 2, 64);
                s += __shfl_xor(s, 4, 64);
                s += __shfl_xor(s, 8, 64);
                part[fm][r] = s;
            }
        // cross-wave (4 N-waves) via LDS
        if (l15 == 0) {
            #pragma unroll
            for (int fm = 0; fm < 2; ++fm)
                #pragma unroll
                for (int r = 0; r < 4; ++r)
                    sums[wm * 32 + fm * 16 + rsub + r][wn] = part[fm][r];
        }
        __syncthreads();
        #pragma unroll
        for (int fm = 0; fm < 2; ++fm) {
            #pragma unroll
            for (int r = 0; r < 4; ++r) {
                const int lrow = wm * 32 + fm * 16 + rsub + r;
                const f32x4 sv = *(const f32x4*)&sums[lrow][0];
                const float tot = sv.x + sv.y + sv.z + sv.w;
                const float scale = 1.f / fmaxf(sqrtf(tot), 1e-12f);
                const int row = m0 + lrow;
                if (row < M) {
                    #pragma unroll
                    for (int fn = 0; fn < 4; ++fn) {
                        const int col = wn * 64 + fn * 16 + l15;
                        Out[(size_t)row * 256 + col] = acc[fm][fn][r] * scale;
                    }
                }
            }
        }
    }
}

extern "C" void kernel_launch(void* const* d_in, const int* in_sizes, int n_in,
                              void* d_out, int out_size, void* d_ws, size_t ws_size,
                              hipStream_t stream)
{
    const float* X         = (const float*)d_in[0];
    const int*   sub_nodes = (const int*)d_in[1];
    const int*   nbr       = (const int*)d_in[2];
    const int*   g2s       = (const int*)d_in[3];
    const float* Wn        = (const float*)d_in[4];
    const float* bn        = (const float*)d_in[5];
    const float* Wf        = (const float*)d_in[6];
    const float* bfin      = (const float*)d_in[7];
    float*       out       = (float*)d_out;

    const int M = out_size / 256;                 // 50000 rows

    // workspace (bf16): Xb | h_b | mean_b | Wnb | Wfb   (~77 MB)
    u16* Xb     = (u16*)d_ws;
    u16* h_b    = Xb     + (size_t)M * 256;
    u16* mean_b = h_b    + (size_t)M * 256;
    u16* Wnb    = mean_b + (size_t)M * 256;
    u16* Wfb    = Wnb    + 65536;

    dim3 b256(256), b512(512);

    k_cast_w<<<768, b256, 0, stream>>>(Wn, Wf, Wnb, Wfb);

    const int nx4 = M * 64;                       // float4 count of X
    k_cast_x<<<(nx4 + 255) / 256, b256, 0, stream>>>(X, Xb, nx4);

    const int gatherBlocks = (M + 7) / 8;         // 8 rows per 4-wave block
    k_gather_mean<<<gatherBlocks, b256, 0, stream>>>(Xb, sub_nodes, nbr, g2s, mean_b, M);

    const int gBlocks = (M + 63) / 64;            // BM=64 -> 782 blocks
    k_gemm<256, 0><<<gBlocks, b512, 0, stream>>>(mean_b, nullptr, Wnb, bn, h_b, nullptr, M);
    k_gemm<512, 1><<<gBlocks, b512, 0, stream>>>(Xb, h_b, Wfb, bfin, nullptr, out, M);
}

// Round 12
// 203.927 us; speedup vs baseline: 1.1285x; 1.1285x over previous
//
#include <hip/hip_runtime.h>
#include <hip/hip_bf16.h>

#define KNBR 20

typedef unsigned short u16;
typedef __attribute__((ext_vector_type(8))) short bf16x8;   // 8 bf16 = 4 VGPR
typedef __attribute__((ext_vector_type(4))) float f32x4;    // MFMA C/D frag

// ---- runtime index-width detection (proven in round 5) ----
__device__ __forceinline__ bool idx_is64(const unsigned int* w) {
    return (w[1] | w[3] | w[5] | w[7] | w[9] | w[11] | w[13] | w[15]) == 0u;
}
__device__ __forceinline__ int idx_at(const int* p, bool is64, long long i) {
    return is64 ? p[2 * i] : p[i];
}

__device__ __forceinline__ u16 f2bf(float x) {
    union { __hip_bfloat16 b; u16 u; } cv;
    cv.b = __float2bfloat16(x);
    return cv.u;
}
__device__ __forceinline__ float blo2f(unsigned int w) {      // low bf16 -> f32
    union { float f; unsigned int i; } c; c.i = w << 16; return c.f;
}
__device__ __forceinline__ float bhi2f(unsigned int w) {      // high bf16 -> f32
    union { float f; unsigned int i; } c; c.i = w & 0xffff0000u; return c.f;
}

// ---------------- K0a: cast weights fp32 -> bf16 (tiny) ----------------
__global__ void __launch_bounds__(256) k_cast_w(
    const float* __restrict__ Wn, const float* __restrict__ Wf,
    u16* __restrict__ Wnb, u16* __restrict__ Wfb)
{
    int i = blockIdx.x * 256 + threadIdx.x;      // 196608 total
    if (i < 65536)       Wnb[i] = f2bf(Wn[i]);
    else if (i < 196608) Wfb[i - 65536] = f2bf(Wf[i - 65536]);
}

// ---------------- K0b: cast X fp32 -> bf16 (float4 -> ushort4 per thread) ----
__global__ void __launch_bounds__(256) k_cast_x(
    const float* __restrict__ X, u16* __restrict__ Xb, int n4)
{
    int i = blockIdx.x * 256 + threadIdx.x;
    if (i < n4) {
        float4 v = ((const float4*)X)[i];
        ushort4 o;
        o.x = f2bf(v.x); o.y = f2bf(v.y); o.z = f2bf(v.z); o.w = f2bf(v.w);
        ((ushort4*)Xb)[i] = o;
    }
}

// ---------------- K1: gather-mean over bf16 X -> bf16 mean ----------------
// 2 rows per wave: half-wave (32 lanes) x 16B = one 512B bf16 row per gather.
__global__ void __launch_bounds__(256) k_gather_mean(
    const u16* __restrict__ Xb, const int* __restrict__ sub_nodes,
    const int* __restrict__ nbr, const int* __restrict__ g2s,
    u16* __restrict__ mean_b, int M)
{
    const bool is64 = idx_is64((const unsigned int*)nbr);
    const int lane = threadIdx.x & 63;
    const int wid  = threadIdx.x >> 6;       // wave in block: 0..3
    const int half = lane >> 5;              // 0/1: which row of the pair
    const int l31  = lane & 31;
    const int row  = blockIdx.x * 8 + wid * 2 + half;
    const int rowc = (row < M) ? row : (M - 1);

    const int g = idx_at(sub_nodes, is64, rowc);
    int s_my = rowc;
    if (l31 < KNBR) {
        int nid = idx_at(nbr, is64, (long long)g * KNBR + l31);
        int s   = idx_at(g2s, is64, nid);
        s_my = (s < 0) ? rowc : s;
    }

    float acc[8] = {0.f, 0.f, 0.f, 0.f, 0.f, 0.f, 0.f, 0.f};
    const int sbase = half << 5;             // shfl source base for this half
    #pragma unroll
    for (int k = 0; k < KNBR; ++k) {
        const int sk = __shfl(s_my, sbase + k, 64);
        const uint4 v = ((const uint4*)(Xb + (size_t)sk * 256))[l31];
        acc[0] += blo2f(v.x); acc[1] += bhi2f(v.x);
        acc[2] += blo2f(v.y); acc[3] += bhi2f(v.y);
        acc[4] += blo2f(v.z); acc[5] += bhi2f(v.z);
        acc[6] += blo2f(v.w); acc[7] += bhi2f(v.w);
    }
    if (row < M) {
        const float inv = 1.0f / (float)KNBR;
        uint4 o;
        o.x = (unsigned)f2bf(acc[0] * inv) | ((unsigned)f2bf(acc[1] * inv) << 16);
        o.y = (unsigned)f2bf(acc[2] * inv) | ((unsigned)f2bf(acc[3] * inv) << 16);
        o.z = (unsigned)f2bf(acc[4] * inv) | ((unsigned)f2bf(acc[5] * inv) << 16);
        o.w = (unsigned)f2bf(acc[6] * inv) | ((unsigned)f2bf(acc[7] * inv) << 16);
        ((uint4*)(mean_b + (size_t)row * 256))[l31] = o;
    }
}

// ---------------- K2/K3: MFMA GEMM  C = relu(A @ W^T + bias) ----------------
// BM=128 (round-10 structure) + ping-pong register prefetch.
// Round-11 diagnosis: VGPR=68 left 4 regs for operands after the 64-reg acc;
// every global load serialized at full L2 latency (MfmaUtil 5.5%).
// Fix: __launch_bounds__(512,2) frees the allocator (~150 VGPR) and the
// explicit 2-set prefetch keeps a full K-step of loads in flight under MFMA.
// Block: 512 thr = 8 waves (2M x 4N), wave = 64x64, BM=128, BN=256 (full row).
// MODE 0: relu -> bf16 Hb.   MODE 1: relu -> row-L2-normalize -> fp32 Out.

#define GLOAD(AF, BF, t) do {                                                  \
    const u16* Asrc_ = (KTOT == 512 && (t) >= 8) ? A1 : A0;                    \
    const int kc_ = ((t) & 7) * 32;                                            \
    _Pragma("unroll")                                                          \
    for (int fm_ = 0; fm_ < 4; ++fm_)                                          \
        AF[fm_] = *(const bf16x8*)(Asrc_ + (size_t)ra[fm_] * 256 + kc_ + lk8); \
    _Pragma("unroll")                                                          \
    for (int fn_ = 0; fn_ < 4; ++fn_)                                          \
        BF[fn_] = *(const bf16x8*)(bbase + (size_t)fn_ * 16 * KTOT + (t) * 32);\
} while (0)

#define DOMFMA(AF, BF) do {                                                    \
    _Pragma("unroll")                                                          \
    for (int fm_ = 0; fm_ < 4; ++fm_)                                          \
        _Pragma("unroll")                                                      \
        for (int fn_ = 0; fn_ < 4; ++fn_)                                      \
            acc[fm_][fn_] = __builtin_amdgcn_mfma_f32_16x16x32_bf16(           \
                AF[fm_], BF[fn_], acc[fm_][fn_], 0, 0, 0);                     \
} while (0)

template<int KTOT, int MODE>
__global__ void __launch_bounds__(512, 2) k_gemm(
    const u16* __restrict__ A0, const u16* __restrict__ A1,
    const u16* __restrict__ B, const float* __restrict__ bias,
    u16* __restrict__ Hb, float* __restrict__ Out, int M)
{
    const int t    = threadIdx.x;
    const int lane = t & 63;
    const int w    = t >> 6;        // 0..7
    const int wm   = w >> 2;        // 0..1  (M dir)
    const int wn   = w & 3;         // 0..3  (N dir)
    const int l15  = lane & 15;
    const int lk8  = (lane >> 4) << 3;   // k sub-offset: 0,8,16,24
    const int rsub = (lane >> 4) << 2;   // C row sub-offset: 0,4,8,12
    const int m0   = blockIdx.x * 128;

    int ra[4];                           // clamped A rows per m-fragment
    #pragma unroll
    for (int fm = 0; fm < 4; ++fm) {
        int r = m0 + wm * 64 + fm * 16 + l15;
        ra[fm] = (r < M) ? r : (M - 1);
    }

    f32x4 acc[4][4];
    #pragma unroll
    for (int i = 0; i < 4; ++i)
        #pragma unroll
        for (int j = 0; j < 4; ++j)
            acc[i][j] = (f32x4)(0.f);

    // B fragment rows: W[wn*64 + fn*16 + l15][k], 16B contiguous per lane
    const u16* bbase = B + (size_t)(wn * 64 + l15) * KTOT + lk8;

    constexpr int NSTEP = KTOT / 32;
    bf16x8 afA[4], bfrA[4], afB[4], bfrB[4];

    GLOAD(afA, bfrA, 0);
    #pragma unroll
    for (int st = 0; st < NSTEP; ++st) {
        if ((st & 1) == 0) {
            if (st + 1 < NSTEP) GLOAD(afB, bfrB, st + 1);
            DOMFMA(afA, bfrA);
        } else {
            if (st + 1 < NSTEP) GLOAD(afA, bfrA, st + 1);
            DOMFMA(afB, bfrB);
        }
    }

    if (MODE == 0) {
        // relu -> bf16 h
        #pragma unroll
        for (int fn = 0; fn < 4; ++fn) {
            const int col = wn * 64 + fn * 16 + l15;
            const float bv = bias[col];
            #pragma unroll
            for (int fm = 0; fm < 4; ++fm) {
                const int rb = m0 + wm * 64 + fm * 16 + rsub;
                #pragma unroll
                for (int r = 0; r < 4; ++r) {
                    const int row = rb + r;
                    if (row < M) {
                        float v = fmaxf(acc[fm][fn][r] + bv, 0.f);
                        Hb[(size_t)row * 256 + col] = f2bf(v);
                    }
                }
            }
        }
    } else {
        // relu -> row L2-normalize -> fp32 out (BN==256 covers full row)
        __shared__ __align__(16) float sums[128][4];
        float part[4][4];
        #pragma unroll
        for (int fm = 0; fm < 4; ++fm)
            #pragma unroll
            for (int r = 0; r < 4; ++r)
                part[fm][r] = 0.f;

        #pragma unroll
        for (int fn = 0; fn < 4; ++fn) {
            const float bv = bias[wn * 64 + fn * 16 + l15];
            #pragma unroll
            for (int fm = 0; fm < 4; ++fm)
                #pragma unroll
                for (int r = 0; r < 4; ++r) {
                    float v = fmaxf(acc[fm][fn][r] + bv, 0.f);
                    acc[fm][fn][r] = v;
                    part[fm][r] += v * v;
                }
        }
        // sum over the wave's 64 cols (16 col-lanes x 4 fn already in-reg)
        #pragma unroll
        for (int fm = 0; fm < 4; ++fm)
            #pragma unroll
            for (int r = 0; r < 4; ++r) {
                float s = part[fm][r];
                s += __shfl_xor(s, 1, 64);
                s += __shfl_xor(s, 2, 64);
                s += __shfl_xor(s, 4, 64);
                s += __shfl_xor(s, 8, 64);
                part[fm][r] = s;
            }
        // cross-wave (4 N-waves) via LDS
        if (l15 == 0) {
            #pragma unroll
            for (int fm = 0; fm < 4; ++fm)
                #pragma unroll
                for (int r = 0; r < 4; ++r)
                    sums[wm * 64 + fm * 16 + rsub + r][wn] = part[fm][r];
        }
        __syncthreads();
        #pragma unroll
        for (int fm = 0; fm < 4; ++fm) {
            #pragma unroll
            for (int r = 0; r < 4; ++r) {
                const int lrow = wm * 64 + fm * 16 + rsub + r;
                const f32x4 sv = *(const f32x4*)&sums[lrow][0];
                const float tot = sv.x + sv.y + sv.z + sv.w;
                const float scale = 1.f / fmaxf(sqrtf(tot), 1e-12f);
                const int row = m0 + lrow;
                if (row < M) {
                    #pragma unroll
                    for (int fn = 0; fn < 4; ++fn) {
                        const int col = wn * 64 + fn * 16 + l15;
                        Out[(size_t)row * 256 + col] = acc[fm][fn][r] * scale;
                    }
                }
            }
        }
    }
}

extern "C" void kernel_launch(void* const* d_in, const int* in_sizes, int n_in,
                              void* d_out, int out_size, void* d_ws, size_t ws_size,
                              hipStream_t stream)
{
    const float* X         = (const float*)d_in[0];
    const int*   sub_nodes = (const int*)d_in[1];
    const int*   nbr       = (const int*)d_in[2];
    const int*   g2s       = (const int*)d_in[3];
    const float* Wn        = (const float*)d_in[4];
    const float* bn        = (const float*)d_in[5];
    const float* Wf        = (const float*)d_in[6];
    const float* bfin      = (const float*)d_in[7];
    float*       out       = (float*)d_out;

    const int M = out_size / 256;                 // 50000 rows

    // workspace (bf16): Xb | h_b | mean_b | Wnb | Wfb   (~77 MB)
    u16* Xb     = (u16*)d_ws;
    u16* h_b    = Xb     + (size_t)M * 256;
    u16* mean_b = h_b    + (size_t)M * 256;
    u16* Wnb    = mean_b + (size_t)M * 256;
    u16* Wfb    = Wnb    + 65536;

    dim3 b256(256), b512(512);

    k_cast_w<<<768, b256, 0, stream>>>(Wn, Wf, Wnb, Wfb);

    const int nx4 = M * 64;                       // float4 count of X
    k_cast_x<<<(nx4 + 255) / 256, b256, 0, stream>>>(X, Xb, nx4);

    const int gatherBlocks = (M + 7) / 8;         // 8 rows per 4-wave block
    k_gather_mean<<<gatherBlocks, b256, 0, stream>>>(Xb, sub_nodes, nbr, g2s, mean_b, M);

    const int gBlocks = (M + 127) / 128;          // BM=128 -> 391 blocks
    k_gemm<256, 0><<<gBlocks, b512, 0, stream>>>(mean_b, nullptr, Wnb, bn, h_b, nullptr, M);
    k_gemm<512, 1><<<gBlocks, b512, 0, stream>>>(Xb, h_b, Wfb, bfin, nullptr, out, M);
}

// Round 13
// 145.655 us; speedup vs baseline: 1.5800x; 1.4001x over previous
//
#include <hip/hip_runtime.h>
#include <hip/hip_bf16.h>

#define KNBR 20

typedef unsigned short u16;
typedef __attribute__((ext_vector_type(8))) short bf16x8;   // 8 bf16 = 4 VGPR
typedef __attribute__((ext_vector_type(4))) float f32x4;    // MFMA C/D frag

// async global->LDS, 16B per lane; LDS dest = wave-uniform base + lane*16
#define GLDS16(gsrc, ldst)                                                     \
    __builtin_amdgcn_global_load_lds(                                          \
        (const __attribute__((address_space(1))) unsigned int*)(const void*)(gsrc), \
        (__attribute__((address_space(3))) unsigned int*)(void*)(ldst), 16, 0, 0)

// ---- runtime index-width detection (proven in round 5) ----
__device__ __forceinline__ bool idx_is64(const unsigned int* w) {
    return (w[1] | w[3] | w[5] | w[7] | w[9] | w[11] | w[13] | w[15]) == 0u;
}
__device__ __forceinline__ int idx_at(const int* p, bool is64, long long i) {
    return is64 ? p[2 * i] : p[i];
}

__device__ __forceinline__ u16 f2bf(float x) {
    union { __hip_bfloat16 b; u16 u; } cv;
    cv.b = __float2bfloat16(x);
    return cv.u;
}
__device__ __forceinline__ float blo2f(unsigned int w) {      // low bf16 -> f32
    union { float f; unsigned int i; } c; c.i = w << 16; return c.f;
}
__device__ __forceinline__ float bhi2f(unsigned int w) {      // high bf16 -> f32
    union { float f; unsigned int i; } c; c.i = w & 0xffff0000u; return c.f;
}

// ---------------- K0a: cast weights fp32 -> bf16 (tiny) ----------------
__global__ void __launch_bounds__(256) k_cast_w(
    const float* __restrict__ Wn, const float* __restrict__ Wf,
    u16* __restrict__ Wnb, u16* __restrict__ Wfb)
{
    int i = blockIdx.x * 256 + threadIdx.x;      // 196608 total
    if (i < 65536)       Wnb[i] = f2bf(Wn[i]);
    else if (i < 196608) Wfb[i - 65536] = f2bf(Wf[i - 65536]);
}

// ---------------- K0b: cast X fp32 -> bf16 (float4 -> ushort4 per thread) ----
__global__ void __launch_bounds__(256) k_cast_x(
    const float* __restrict__ X, u16* __restrict__ Xb, int n4)
{
    int i = blockIdx.x * 256 + threadIdx.x;
    if (i < n4) {
        float4 v = ((const float4*)X)[i];
        ushort4 o;
        o.x = f2bf(v.x); o.y = f2bf(v.y); o.z = f2bf(v.z); o.w = f2bf(v.w);
        ((ushort4*)Xb)[i] = o;
    }
}

// ---------------- K1: gather-mean over bf16 X -> bf16 mean ----------------
// 2 rows per wave: half-wave (32 lanes) x 16B = one 512B bf16 row per gather.
__global__ void __launch_bounds__(256) k_gather_mean(
    const u16* __restrict__ Xb, const int* __restrict__ sub_nodes,
    const int* __restrict__ nbr, const int* __restrict__ g2s,
    u16* __restrict__ mean_b, int M)
{
    const bool is64 = idx_is64((const unsigned int*)nbr);
    const int lane = threadIdx.x & 63;
    const int wid  = threadIdx.x >> 6;       // wave in block: 0..3
    const int half = lane >> 5;              // 0/1: which row of the pair
    const int l31  = lane & 31;
    const int row  = blockIdx.x * 8 + wid * 2 + half;
    const int rowc = (row < M) ? row : (M - 1);

    const int g = idx_at(sub_nodes, is64, rowc);
    int s_my = rowc;
    if (l31 < KNBR) {
        int nid = idx_at(nbr, is64, (long long)g * KNBR + l31);
        int s   = idx_at(g2s, is64, nid);
        s_my = (s < 0) ? rowc : s;
    }

    float acc[8] = {0.f, 0.f, 0.f, 0.f, 0.f, 0.f, 0.f, 0.f};
    const int sbase = half << 5;             // shfl source base for this half
    #pragma unroll
    for (int k = 0; k < KNBR; ++k) {
        const int sk = __shfl(s_my, sbase + k, 64);
        const uint4 v = ((const uint4*)(Xb + (size_t)sk * 256))[l31];
        acc[0] += blo2f(v.x); acc[1] += bhi2f(v.x);
        acc[2] += blo2f(v.y); acc[3] += bhi2f(v.y);
        acc[4] += blo2f(v.z); acc[5] += bhi2f(v.z);
        acc[6] += blo2f(v.w); acc[7] += bhi2f(v.w);
    }
    if (row < M) {
        const float inv = 1.0f / (float)KNBR;
        uint4 o;
        o.x = (unsigned)f2bf(acc[0] * inv) | ((unsigned)f2bf(acc[1] * inv) << 16);
        o.y = (unsigned)f2bf(acc[2] * inv) | ((unsigned)f2bf(acc[3] * inv) << 16);
        o.z = (unsigned)f2bf(acc[4] * inv) | ((unsigned)f2bf(acc[5] * inv) << 16);
        o.w = (unsigned)f2bf(acc[6] * inv) | ((unsigned)f2bf(acc[7] * inv) << 16);
        ((uint4*)(mean_b + (size_t)row * 256))[l31] = o;
    }
}

// ---------------- K2/K3: LDS-staged MFMA GEMM  C = relu(A @ W^T + bias) ------
// m97-style: double-buffered LDS tiles filled by global_load_lds (width 16),
// ds_read_b128 fragments, 2-barrier K-loop. Round-12 evidence: direct
// global->MFMA loads serialize at minimal VGPR (MfmaUtil 5.5%); the compiler
// pipelines ds_read->MFMA well, so route the stream through LDS.
// Block: 512 thr = 8 waves (2M x 4N), wave = 64x64, BM=128, BN=256, BK=32.
// MODE 0: relu -> bf16 Hb.   MODE 1: relu -> row-L2-normalize -> fp32 Out.
template<int KTOT, int MODE>
__global__ void __launch_bounds__(512) k_gemm(
    const u16* __restrict__ A0, const u16* __restrict__ A1,
    const u16* __restrict__ B, const float* __restrict__ bias,
    u16* __restrict__ Hb, float* __restrict__ Out, int M)
{
    __shared__ u16 As[2][128 * 32];   // 8 KB per buffer
    __shared__ u16 Bs[2][256 * 32];   // 16 KB per buffer

    const int t    = threadIdx.x;
    const int lane = t & 63;
    const int w    = t >> 6;        // 0..7
    const int wm   = w >> 2;        // 0..1  (M dir)
    const int wn   = w & 3;         // 0..3  (N dir)
    const int l15  = lane & 15;
    const int lk8  = (lane >> 4) << 3;   // k sub-offset: 0,8,16,24
    const int rsub = (lane >> 4) << 2;   // C row sub-offset: 0,4,8,12
    const int m0   = blockIdx.x * 128;

    // ---- staging geometry (per thread / per wave) ----
    // A-tile: 512 chunks of 16B; chunk t -> row t>>2, slot (t&3)*8 u16.
    const int aRow  = t >> 2;
    const int aCol  = (t & 3) * 8;
    int aRowG = m0 + aRow; aRowG = (aRowG < M) ? aRowG : (M - 1);
    // B-tile: 1024 chunks; thread covers chunk t (rows 0..127) and 512+t.
    const int bRow0 = t >> 2;
    const int bRow1 = (t >> 2) + 128;
    const int bCol  = (t & 3) * 8;

#define STAGE(buf, tt) do {                                                    \
    const u16* Asrc_ = (KTOT == 512 && (tt) >= 8) ? A1 : A0;                   \
    const int kcA_ = ((tt) & 7) * 32;                                          \
    GLDS16(Asrc_ + (size_t)aRowG * 256 + kcA_ + aCol, &As[buf][w * 512]);      \
    GLDS16(B + (size_t)bRow0 * KTOT + (tt) * 32 + bCol, &Bs[buf][w * 512]);    \
    GLDS16(B + (size_t)bRow1 * KTOT + (tt) * 32 + bCol, &Bs[buf][4096 + w * 512]); \
} while (0)

    f32x4 acc[4][4];
    #pragma unroll
    for (int i = 0; i < 4; ++i)
        #pragma unroll
        for (int j = 0; j < 4; ++j)
            acc[i][j] = (f32x4)(0.f);

    constexpr int NT = KTOT / 32;

    STAGE(0, 0);
    __syncthreads();

    #pragma unroll
    for (int tt = 0; tt < NT; ++tt) {
        const int cur = tt & 1;
        if (tt + 1 < NT) STAGE(cur ^ 1, tt + 1);

        bf16x8 af[4], bfr[4];
        #pragma unroll
        for (int fm = 0; fm < 4; ++fm)
            af[fm] = *(const bf16x8*)&As[cur][(wm * 64 + fm * 16 + l15) * 32 + lk8];
        #pragma unroll
        for (int fn = 0; fn < 4; ++fn)
            bfr[fn] = *(const bf16x8*)&Bs[cur][(wn * 64 + fn * 16 + l15) * 32 + lk8];
        #pragma unroll
        for (int fm = 0; fm < 4; ++fm)
            #pragma unroll
            for (int fn = 0; fn < 4; ++fn)
                acc[fm][fn] = __builtin_amdgcn_mfma_f32_16x16x32_bf16(
                    af[fm], bfr[fn], acc[fm][fn], 0, 0, 0);

        __syncthreads();   // drains staged loads for buf cur^1; protects reuse
    }
#undef STAGE

    if (MODE == 0) {
        // relu -> bf16 h
        #pragma unroll
        for (int fn = 0; fn < 4; ++fn) {
            const int col = wn * 64 + fn * 16 + l15;
            const float bv = bias[col];
            #pragma unroll
            for (int fm = 0; fm < 4; ++fm) {
                const int rb = m0 + wm * 64 + fm * 16 + rsub;
                #pragma unroll
                for (int r = 0; r < 4; ++r) {
                    const int row = rb + r;
                    if (row < M) {
                        float v = fmaxf(acc[fm][fn][r] + bv, 0.f);
                        Hb[(size_t)row * 256 + col] = f2bf(v);
                    }
                }
            }
        }
    } else {
        // relu -> row L2-normalize -> fp32 out (BN==256 covers full row)
        __shared__ __align__(16) float sums[128][4];
        float part[4][4];
        #pragma unroll
        for (int fm = 0; fm < 4; ++fm)
            #pragma unroll
            for (int r = 0; r < 4; ++r)
                part[fm][r] = 0.f;

        #pragma unroll
        for (int fn = 0; fn < 4; ++fn) {
            const float bv = bias[wn * 64 + fn * 16 + l15];
            #pragma unroll
            for (int fm = 0; fm < 4; ++fm)
                #pragma unroll
                for (int r = 0; r < 4; ++r) {
                    float v = fmaxf(acc[fm][fn][r] + bv, 0.f);
                    acc[fm][fn][r] = v;
                    part[fm][r] += v * v;
                }
        }
        // sum over the wave's 64 cols (16 col-lanes x 4 fn already in-reg)
        #pragma unroll
        for (int fm = 0; fm < 4; ++fm)
            #pragma unroll
            for (int r = 0; r < 4; ++r) {
                float s = part[fm][r];
                s += __shfl_xor(s, 1, 64);
                s += __shfl_xor(s, 2, 64);
                s += __shfl_xor(s, 4, 64);
                s += __shfl_xor(s, 8, 64);
                part[fm][r] = s;
            }
        // cross-wave (4 N-waves) via LDS
        if (l15 == 0) {
            #pragma unroll
            for (int fm = 0; fm < 4; ++fm)
                #pragma unroll
                for (int r = 0; r < 4; ++r)
                    sums[wm * 64 + fm * 16 + rsub + r][wn] = part[fm][r];
        }
        __syncthreads();
        #pragma unroll
        for (int fm = 0; fm < 4; ++fm) {
            #pragma unroll
            for (int r = 0; r < 4; ++r) {
                const int lrow = wm * 64 + fm * 16 + rsub + r;
                const f32x4 sv = *(const f32x4*)&sums[lrow][0];
                const float tot = sv.x + sv.y + sv.z + sv.w;
                const float scale = 1.f / fmaxf(sqrtf(tot), 1e-12f);
                const int row = m0 + lrow;
                if (row < M) {
                    #pragma unroll
                    for (int fn = 0; fn < 4; ++fn) {
                        const int col = wn * 64 + fn * 16 + l15;
                        Out[(size_t)row * 256 + col] = acc[fm][fn][r] * scale;
                    }
                }
            }
        }
    }
}

extern "C" void kernel_launch(void* const* d_in, const int* in_sizes, int n_in,
                              void* d_out, int out_size, void* d_ws, size_t ws_size,
                              hipStream_t stream)
{
    const float* X         = (const float*)d_in[0];
    const int*   sub_nodes = (const int*)d_in[1];
    const int*   nbr       = (const int*)d_in[2];
    const int*   g2s       = (const int*)d_in[3];
    const float* Wn        = (const float*)d_in[4];
    const float* bn        = (const float*)d_in[5];
    const float* Wf        = (const float*)d_in[6];
    const float* bfin      = (const float*)d_in[7];
    float*       out       = (float*)d_out;

    const int M = out_size / 256;                 // 50000 rows

    // workspace (bf16): Xb | h_b | mean_b | Wnb | Wfb   (~77 MB)
    u16* Xb     = (u16*)d_ws;
    u16* h_b    = Xb     + (size_t)M * 256;
    u16* mean_b = h_b    + (size_t)M * 256;
    u16* Wnb    = mean_b + (size_t)M * 256;
    u16* Wfb    = Wnb    + 65536;

    dim3 b256(256), b512(512);

    k_cast_w<<<768, b256, 0, stream>>>(Wn, Wf, Wnb, Wfb);

    const int nx4 = M * 64;                       // float4 count of X
    k_cast_x<<<(nx4 + 255) / 256, b256, 0, stream>>>(X, Xb, nx4);

    const int gatherBlocks = (M + 7) / 8;         // 8 rows per 4-wave block
    k_gather_mean<<<gatherBlocks, b256, 0, stream>>>(Xb, sub_nodes, nbr, g2s, mean_b, M);

    const int gBlocks = (M + 127) / 128;          // BM=128 -> 391 blocks
    k_gemm<256, 0><<<gBlocks, b512, 0, stream>>>(mean_b, nullptr, Wnb, bn, h_b, nullptr, M);
    k_gemm<512, 1><<<gBlocks, b512, 0, stream>>>(Xb, h_b, Wfb, bfin, nullptr, out, M);
}

// Round 14
// 128.963 us; speedup vs baseline: 1.7845x; 1.1294x over previous
//
#include <hip/hip_runtime.h>
#include <hip/hip_bf16.h>

#define KNBR 20
typedef unsigned short u16;
typedef __attribute__((ext_vector_type(8))) short bf16x8;   // 8 bf16 = 4 VGPR
typedef __attribute__((ext_vector_type(4))) float f32x4;    // MFMA C/D frag

// async global->LDS, 16B/lane; LDS dest wave-uniform base + lane*16 (m104)
#define GLDS16(gsrc, ldst)                                                     \
    __builtin_amdgcn_global_load_lds(                                          \
        (const __attribute__((address_space(1))) unsigned int*)(const void*)(gsrc), \
        (__attribute__((address_space(3))) unsigned int*)(void*)(ldst), 16, 0, 0)

// ---- runtime index-width detection (proven round 5) ----
__device__ __forceinline__ bool idx_is64(const unsigned int* w) {
    return (w[1] | w[3] | w[5] | w[7] | w[9] | w[11] | w[13] | w[15]) == 0u;
}
__device__ __forceinline__ int idx_at(const int* p, bool is64, long long i) {
    return is64 ? p[2 * i] : p[i];
}
__device__ __forceinline__ u16 f2bf(float x) {
    union { __hip_bfloat16 b; u16 u; } cv;
    cv.b = __float2bfloat16(x);
    return cv.u;
}
__device__ __forceinline__ float blo2f(unsigned int w) {
    union { float f; unsigned int i; } c; c.i = w << 16; return c.f;
}
__device__ __forceinline__ float bhi2f(unsigned int w) {
    union { float f; unsigned int i; } c; c.i = w & 0xffff0000u; return c.f;
}

// ---------------- K0: all fp32->bf16 casts in one kernel ----------------
__global__ void __launch_bounds__(256) k_cast(
    const float* __restrict__ X, const float* __restrict__ Wn,
    const float* __restrict__ Wf, u16* __restrict__ Xb,
    u16* __restrict__ Wnb, u16* __restrict__ Wfb, int nx4)
{
    const int i = blockIdx.x * 256 + threadIdx.x;
    const float4* src; ushort4* dst; int j;
    if (i < nx4)                     { src = (const float4*)X;  dst = (ushort4*)Xb;  j = i; }
    else if (i < nx4 + 16384)        { src = (const float4*)Wn; dst = (ushort4*)Wnb; j = i - nx4; }
    else if (i < nx4 + 16384 + 32768){ src = (const float4*)Wf; dst = (ushort4*)Wfb; j = i - nx4 - 16384; }
    else return;
    const float4 v = src[j];
    ushort4 o;
    o.x = f2bf(v.x); o.y = f2bf(v.y); o.z = f2bf(v.z); o.w = f2bf(v.w);
    dst[j] = o;
}

// ---------------- K1: fully fused gather+mean -> GEMM1 -> GEMM2 -> normalize -
// Block-local pipeline, BM=64 rows, 256 thr = 4 waves (wave: 64 rows x 64 cols).
// No inter-block deps; blocks at different phases overlap memory (gather) with
// MFMA across the CU. LDS 73KB -> 2 blocks/CU.
// Swizzles: mh [64][256] chunk c -> c^(row&7); B/X tiles [r][32k] chunk c ->
// c^(r&3), applied on the *global source* of global_load_lds (m173 pattern).
__global__ void __launch_bounds__(256, 2) k_fused(
    const u16* __restrict__ Xb, const int* __restrict__ sub_nodes,
    const int* __restrict__ nbr, const int* __restrict__ g2s,
    const u16* __restrict__ Wnb, const float* __restrict__ bn,
    const u16* __restrict__ Wfb, const float* __restrict__ bfin,
    float* __restrict__ Out, int M)
{
    __shared__ u16 mh[64 * 256];                 // 32KB: mean, then h
    __shared__ u16 Bs[2][256 * 32];              // 16KB x2
    __shared__ u16 Xs[2][64 * 32];               // 4KB x2
    __shared__ __align__(16) float sums[64][4];  // 1KB

    const int t    = threadIdx.x;
    const int lane = t & 63;
    const int w    = t >> 6;             // wave 0..3 == N-chunk of 64 cols
    const int l15  = lane & 15;
    const int lk8  = (lane >> 4) << 3;   // 0,8,16,24
    const int rsub = (lane >> 4) << 2;   // 0,4,8,12
    const int r7   = l15 & 7;            // (row&7) for rows fm*16+l15
    const int r3   = l15 & 3;            // (row&3)
    const int sRow = lane >> 2;          // staging: row-in-group 0..15
    const int sSlot= lane & 3;           // staging: chunk 0..3
    const int m0   = blockIdx.x * 64;

// stage 16KB B-tile (256 rows x 32k), linear LDS, source chunk-swizzled c^(r&3)
#define STAGE_B(buf, Bp, KT, tt) do {                                          \
    _Pragma("unroll")                                                          \
    for (int rp_ = 0; rp_ < 4; ++rp_) {                                        \
        const int rr_ = (rp_ * 4 + w) * 16 + sRow;                             \
        const int cc_ = sSlot ^ (rr_ & 3);                                     \
        GLDS16(Bp + (size_t)rr_ * KT + (tt) * 32 + cc_ * 8,                    \
               &Bs[buf][(rp_ * 4 + w) * 512]);                                 \
    } } while (0)

// stage 4KB X-tile (64 rows x 32k)
#define STAGE_X(buf, tt) do {                                                  \
    const int rl_ = w * 16 + sRow;                                             \
    int rg_ = m0 + rl_; rg_ = (rg_ < M) ? rg_ : (M - 1);                       \
    const int cc_ = sSlot ^ (rl_ & 3);                                         \
    GLDS16(Xb + (size_t)rg_ * 256 + (tt) * 32 + cc_ * 8, &Xs[buf][w * 512]);   \
} while (0)

    // prefetch GEMM1 B step 0 under the gather
    STAGE_B(0, Wnb, 256, 0);

    // ---- phase G: gather-mean for this block's 64 rows (2 rows/wave/iter) --
    {
        const bool is64 = idx_is64((const unsigned int*)nbr);
        const int half = lane >> 5;
        const int l31  = lane & 31;
        const int sb   = half << 5;
        #pragma unroll 1
        for (int j = 0; j < 8; ++j) {
            const int rl  = w * 16 + j * 2 + half;
            const int row = m0 + rl;
            const int rowc = (row < M) ? row : (M - 1);
            const int g = idx_at(sub_nodes, is64, rowc);
            int s_my = rowc;
            if (l31 < KNBR) {
                int nid = idx_at(nbr, is64, (long long)g * KNBR + l31);
                int s   = idx_at(g2s, is64, nid);
                s_my = (s < 0) ? rowc : s;
            }
            float a0=0.f,a1=0.f,a2=0.f,a3=0.f,a4=0.f,a5=0.f,a6=0.f,a7=0.f;
            #pragma unroll
            for (int k = 0; k < KNBR; ++k) {
                const int sk = __shfl(s_my, sb + k, 64);
                const uint4 v = *(const uint4*)(Xb + (size_t)sk * 256 + l31 * 8);
                a0 += blo2f(v.x); a1 += bhi2f(v.x);
                a2 += blo2f(v.y); a3 += bhi2f(v.y);
                a4 += blo2f(v.z); a5 += bhi2f(v.z);
                a6 += blo2f(v.w); a7 += bhi2f(v.w);
            }
            const float inv = 1.0f / (float)KNBR;
            uint4 o;
            o.x = (unsigned)f2bf(a0*inv) | ((unsigned)f2bf(a1*inv) << 16);
            o.y = (unsigned)f2bf(a2*inv) | ((unsigned)f2bf(a3*inv) << 16);
            o.z = (unsigned)f2bf(a4*inv) | ((unsigned)f2bf(a5*inv) << 16);
            o.w = (unsigned)f2bf(a6*inv) | ((unsigned)f2bf(a7*inv) << 16);
            *(uint4*)&mh[rl * 256 + ((l31 ^ (rl & 7)) << 3)] = o;
        }
    }
    __syncthreads();   // mean in LDS + B1[0] staged

    // ---- phase 1: h = relu(mean @ Wn^T + bn), h -> mh (in place) ----------
    f32x4 acc[4][4];
    #pragma unroll
    for (int i = 0; i < 4; ++i)
        #pragma unroll
        for (int j = 0; j < 4; ++j)
            acc[i][j] = (f32x4)(0.f);

    #pragma unroll
    for (int tt = 0; tt < 8; ++tt) {
        const int cur = tt & 1;
        if (tt < 7) STAGE_B(cur ^ 1, Wnb, 256, tt + 1);
        bf16x8 af[4], bfr[4];
        #pragma unroll
        for (int fm = 0; fm < 4; ++fm)
            af[fm] = *(const bf16x8*)&mh[(fm*16 + l15) * 256 +
                                         (((tt*4 + (lk8 >> 3)) ^ r7) << 3)];
        #pragma unroll
        for (int fn = 0; fn < 4; ++fn)
            bfr[fn] = *(const bf16x8*)&Bs[cur][(w*64 + fn*16 + l15) * 32 +
                                              (((lk8 >> 3) ^ r3) << 3)];
        #pragma unroll
        for (int fm = 0; fm < 4; ++fm)
            #pragma unroll
            for (int fn = 0; fn < 4; ++fn)
                acc[fm][fn] = __builtin_amdgcn_mfma_f32_16x16x32_bf16(
                    af[fm], bfr[fn], acc[fm][fn], 0, 0, 0);
        __syncthreads();
    }

    // prefetch GEMM2 step 0 (Bs[0] free after step 6's barrier; Xs untouched)
    STAGE_B(0, Wfb, 512, 0);
    STAGE_X(0, 0);

    // write h into mh (all mean reads completed at loop-end barrier)
    #pragma unroll
    for (int fn = 0; fn < 4; ++fn) {
        const int col = w * 64 + fn * 16 + l15;
        const float bv = bn[col];
        #pragma unroll
        for (int fm = 0; fm < 4; ++fm)
            #pragma unroll
            for (int r = 0; r < 4; ++r) {
                const int row = fm * 16 + rsub + r;
                const float v = fmaxf(acc[fm][fn][r] + bv, 0.f);
                mh[row * 256 + ((((col >> 3) ^ (row & 7))) << 3) + (col & 7)] = f2bf(v);
            }
    }
    __syncthreads();   // h visible + GEMM2 step-0 tiles staged

    // ---- phase 2: out = normalize(relu([X|h] @ Wf^T + bf)) ----------------
    #pragma unroll
    for (int i = 0; i < 4; ++i)
        #pragma unroll
        for (int j = 0; j < 4; ++j)
            acc[i][j] = (f32x4)(0.f);

    #pragma unroll
    for (int tt = 0; tt < 16; ++tt) {
        const int cur = tt & 1;
        if (tt < 15) {
            STAGE_B(cur ^ 1, Wfb, 512, tt + 1);
            if (tt + 1 < 8) STAGE_X(cur ^ 1, tt + 1);
        }
        bf16x8 af[4], bfr[4];
        if (tt < 8) {
            #pragma unroll
            for (int fm = 0; fm < 4; ++fm)
                af[fm] = *(const bf16x8*)&Xs[cur][(fm*16 + l15) * 32 +
                                                  (((lk8 >> 3) ^ r3) << 3)];
        } else {
            #pragma unroll
            for (int fm = 0; fm < 4; ++fm)
                af[fm] = *(const bf16x8*)&mh[(fm*16 + l15) * 256 +
                                             ((((tt-8)*4 + (lk8 >> 3)) ^ r7) << 3)];
        }
        #pragma unroll
        for (int fn = 0; fn < 4; ++fn)
            bfr[fn] = *(const bf16x8*)&Bs[cur][(w*64 + fn*16 + l15) * 32 +
                                              (((lk8 >> 3) ^ r3) << 3)];
        #pragma unroll
        for (int fm = 0; fm < 4; ++fm)
            #pragma unroll
            for (int fn = 0; fn < 4; ++fn)
                acc[fm][fn] = __builtin_amdgcn_mfma_f32_16x16x32_bf16(
                    af[fm], bfr[fn], acc[fm][fn], 0, 0, 0);
        __syncthreads();
    }

    // epilogue: bias + relu + row-L2-normalize + fp32 store
    float part[4][4];
    #pragma unroll
    for (int fm = 0; fm < 4; ++fm)
        #pragma unroll
        for (int r = 0; r < 4; ++r)
            part[fm][r] = 0.f;
    #pragma unroll
    for (int fn = 0; fn < 4; ++fn) {
        const float bv = bfin[w * 64 + fn * 16 + l15];
        #pragma unroll
        for (int fm = 0; fm < 4; ++fm)
            #pragma unroll
            for (int r = 0; r < 4; ++r) {
                const float v = fmaxf(acc[fm][fn][r] + bv, 0.f);
                acc[fm][fn][r] = v;
                part[fm][r] += v * v;
            }
    }
    #pragma unroll
    for (int fm = 0; fm < 4; ++fm)
        #pragma unroll
        for (int r = 0; r < 4; ++r) {
            float s = part[fm][r];
            s += __shfl_xor(s, 1, 64);
            s += __shfl_xor(s, 2, 64);
            s += __shfl_xor(s, 4, 64);
            s += __shfl_xor(s, 8, 64);
            part[fm][r] = s;
        }
    if (l15 == 0) {
        #pragma unroll
        for (int fm = 0; fm < 4; ++fm)
            #pragma unroll
            for (int r = 0; r < 4; ++r)
                sums[fm * 16 + rsub + r][w] = part[fm][r];
    }
    __syncthreads();
    #pragma unroll
    for (int fm = 0; fm < 4; ++fm)
        #pragma unroll
        for (int r = 0; r < 4; ++r) {
            const int lrow = fm * 16 + rsub + r;
            const f32x4 sv = *(const f32x4*)&sums[lrow][0];
            const float tot = sv.x + sv.y + sv.z + sv.w;
            const float scale = 1.f / fmaxf(sqrtf(tot), 1e-12f);
            const int row = m0 + lrow;
            if (row < M) {
                #pragma unroll
                for (int fn = 0; fn < 4; ++fn)
                    Out[(size_t)row * 256 + w * 64 + fn * 16 + l15] =
                        acc[fm][fn][r] * scale;
            }
        }
#undef STAGE_B
#undef STAGE_X
}

extern "C" void kernel_launch(void* const* d_in, const int* in_sizes, int n_in,
                              void* d_out, int out_size, void* d_ws, size_t ws_size,
                              hipStream_t stream)
{
    const float* X         = (const float*)d_in[0];
    const int*   sub_nodes = (const int*)d_in[1];
    const int*   nbr       = (const int*)d_in[2];
    const int*   g2s       = (const int*)d_in[3];
    const float* Wn        = (const float*)d_in[4];
    const float* bn        = (const float*)d_in[5];
    const float* Wf        = (const float*)d_in[6];
    const float* bfin      = (const float*)d_in[7];
    float*       out       = (float*)d_out;

    const int M = out_size / 256;                 // 50000 rows

    // workspace (bf16): Xb | Wnb | Wfb
    u16* Xb  = (u16*)d_ws;
    u16* Wnb = Xb  + (size_t)M * 256;
    u16* Wfb = Wnb + 65536;

    const int nx4 = M * 64;                       // float4 count of X
    const int castTotal = nx4 + 16384 + 32768;
    k_cast<<<(castTotal + 255) / 256, 256, 0, stream>>>(X, Wn, Wf, Xb, Wnb, Wfb, nx4);

    const int fBlocks = (M + 63) / 64;            // 782 blocks
    k_fused<<<fBlocks, 256, 0, stream>>>(Xb, sub_nodes, nbr, g2s,
                                         Wnb, bn, Wfb, bfin, out, M);
}